// Round 1
// baseline (1628.113 us; speedup 1.0000x reference)
//
#include <hip/hip_runtime.h>

#define N_NODES 100000
#define N_EDGES 1600000
#define D 64
#define NEG_SLOPE 0.2f

// ---------------------------------------------------------------------------
// Kernel 1: per-edge attention score -> exp, accumulate softmax denominator.
// e = leaky_relu(rel[e,:] . attn_e); ex = exp(e); denom[dst[e]] += ex
// (segment_max skipped: softmax is shift-invariant and |e| is small, so
//  exp() cannot overflow — identical math to the reference.)
// ---------------------------------------------------------------------------
__global__ __launch_bounds__(256) void edge_score_kernel(
    const float* __restrict__ rel, const float* __restrict__ attn_e,
    const int* __restrict__ dst, float* __restrict__ ex,
    float* __restrict__ denom)
{
    int e = blockIdx.x * blockDim.x + threadIdx.x;
    if (e >= N_EDGES) return;
    float a0 = attn_e[0], a1 = attn_e[1];
    float2 r = ((const float2*)rel)[e];           // coalesced 8B/lane
    float s = r.x * a0 + r.y * a1;
    s = (s > 0.f) ? s : NEG_SLOPE * s;            // leaky_relu
    float ev = __expf(s);
    ex[e] = ev;
    atomicAdd(&denom[dst[e]], ev);
}

// ---------------------------------------------------------------------------
// Kernel 2: h_neigh[dst] += (ex/denom[dst]) * feat[src]
// 16 threads per edge, float4 per thread (64 floats/row). Accumulates
// directly into d_out (zeroed beforehand), which doubles as h_neigh storage.
// ---------------------------------------------------------------------------
__global__ __launch_bounds__(256) void aggregate_kernel(
    const float* __restrict__ feat, const int* __restrict__ src,
    const int* __restrict__ dst, const float* __restrict__ ex,
    const float* __restrict__ denom, float* __restrict__ out)
{
    int gid = blockIdx.x * blockDim.x + threadIdx.x;   // E*16 = 25.6M < 2^31
    int e = gid >> 4;
    int c = gid & 15;
    if (e >= N_EDGES) return;
    int s = src[e];
    int d = dst[e];
    float a = ex[e] / denom[d];
    float4 v = ((const float4*)feat)[s * 16 + c];      // gather, L2/L3-cached
    float* o = out + (size_t)d * D + c * 4;
    atomicAdd(o + 0, a * v.x);
    atomicAdd(o + 1, a * v.y);
    atomicAdd(o + 2, a * v.z);
    atomicAdd(o + 3, a * v.w);
}

// ---------------------------------------------------------------------------
// Kernel 3: out = feat @ W_self^T + h_neigh @ W_neigh^T + (b_self + b_neigh)
// In-place on d_out (h_neigh staged to LDS first). 4 rows per 256-thread
// block; one wave per row (lanes = 64 output features). Weights transposed
// into LDS with +1 pad -> conflict-free reads (lanes hit consecutive banks).
// ---------------------------------------------------------------------------
__global__ __launch_bounds__(256) void linear_kernel(
    const float* __restrict__ feat, const float* __restrict__ W_self,
    const float* __restrict__ b_self, const float* __restrict__ W_neigh,
    const float* __restrict__ b_neigh, float* __restrict__ out)
{
    __shared__ float Ws[D * (D + 1)];   // Ws[k*(D+1)+o] = W_self[o*D+k]
    __shared__ float Wn[D * (D + 1)];
    __shared__ float fs[4 * D];         // 4 feat rows
    __shared__ float hs[4 * D];         // 4 h_neigh rows

    int tid = threadIdx.x;
    // Stage transposed weights: 4096 elems / 256 threads = 16 iters each.
    #pragma unroll
    for (int i = 0; i < 16; ++i) {
        int idx = tid + i * 256;        // idx = o*64 + k (coalesced read)
        int o = idx >> 6;
        int k = idx & 63;
        Ws[k * (D + 1) + o] = W_self[idx];
        Wn[k * (D + 1) + o] = W_neigh[idx];
    }

    int r0 = blockIdx.x * 4;            // 100000 % 4 == 0: no tail
    // 4 contiguous rows == 256 contiguous floats
    fs[tid] = feat[(size_t)r0 * D + tid];
    hs[tid] = out[(size_t)r0 * D + tid];
    __syncthreads();

    int r = tid >> 6;                   // row within block (wave-uniform)
    int o = tid & 63;                   // output feature (lane)
    float acc = 0.f;
    #pragma unroll
    for (int k = 0; k < D; ++k) {
        acc += fs[r * D + k] * Ws[k * (D + 1) + o];   // fs: broadcast
        acc += hs[r * D + k] * Wn[k * (D + 1) + o];   // Ws/Wn: stride-1 lanes
    }
    out[(size_t)(r0 + r) * D + o] = acc + b_self[o] + b_neigh[o];
}

// ---------------------------------------------------------------------------
extern "C" void kernel_launch(void* const* d_in, const int* in_sizes, int n_in,
                              void* d_out, int out_size, void* d_ws, size_t ws_size,
                              hipStream_t stream) {
    const float* feat    = (const float*)d_in[0];
    const float* rel     = (const float*)d_in[1];
    const float* W_self  = (const float*)d_in[2];
    const float* b_self  = (const float*)d_in[3];
    const float* W_neigh = (const float*)d_in[4];
    const float* b_neigh = (const float*)d_in[5];
    const float* attn_e  = (const float*)d_in[6];
    const int*   src     = (const int*)d_in[7];
    const int*   dst     = (const int*)d_in[8];
    float* out = (float*)d_out;

    float* ex    = (float*)d_ws;            // [E]
    float* denom = ex + N_EDGES;            // [N]

    // ws/out are poisoned 0xAA before every timed launch — zero what we use.
    hipMemsetAsync(denom, 0, N_NODES * sizeof(float), stream);
    hipMemsetAsync(out, 0, (size_t)out_size * sizeof(float), stream);

    edge_score_kernel<<<(N_EDGES + 255) / 256, 256, 0, stream>>>(
        rel, attn_e, dst, ex, denom);

    aggregate_kernel<<<(N_EDGES * 16) / 256, 256, 0, stream>>>(
        feat, src, dst, ex, denom, out);

    linear_kernel<<<N_NODES / 4, 256, 0, stream>>>(
        feat, W_self, b_self, W_neigh, b_neigh, out);
}

// Round 2
// 771.920 us; speedup vs baseline: 2.1092x; 2.1092x over previous
//
#include <hip/hip_runtime.h>

#define N_NODES 100000
#define N_EDGES 1600000
#define D 64
#define NEG_SLOPE 0.2f
#define SCAN_T 1024
#define CHUNK ((N_NODES + SCAN_T - 1) / SCAN_T)   // 98

// ---------------------------------------------------------------------------
// Kernel 1: histogram of edges per destination node.
// ---------------------------------------------------------------------------
__global__ __launch_bounds__(256) void hist_kernel(
    const int* __restrict__ dst, int* __restrict__ cnt)
{
    int e = blockIdx.x * 256 + threadIdx.x;
    if (e < N_EDGES) atomicAdd(&cnt[dst[e]], 1);
}

// ---------------------------------------------------------------------------
// Kernel 2: single-block exclusive scan -> CSR offsets (+ cursor copy).
// 1024 threads, each owns a 98-element chunk; Hillis-Steele over partials.
// ---------------------------------------------------------------------------
__global__ __launch_bounds__(SCAN_T) void scan_kernel(
    const int* __restrict__ cnt, int* __restrict__ offsets,
    int* __restrict__ cursor)
{
    __shared__ int partial[SCAN_T];
    int t = threadIdx.x;
    int lo = t * CHUNK;
    int hi = min(lo + CHUNK, N_NODES);
    int s = 0;
    for (int i = lo; i < hi; ++i) s += cnt[i];
    partial[t] = s;
    __syncthreads();
    for (int d = 1; d < SCAN_T; d <<= 1) {
        int v = (t >= d) ? partial[t - d] : 0;
        __syncthreads();
        partial[t] += v;
        __syncthreads();
    }
    int run = (t == 0) ? 0 : partial[t - 1];   // exclusive prefix of chunk
    for (int i = lo; i < hi; ++i) {
        offsets[i] = run;
        cursor[i] = run;
        run += cnt[i];
    }
    if (t == 0) offsets[N_NODES] = N_EDGES;
}

// ---------------------------------------------------------------------------
// Kernel 3: ticket scatter into CSR order. Stores {src, exp(e)} packed as
// int2 so the aggregation loop does ONE 8B broadcast load per edge.
// segment_max skipped: softmax is shift-invariant and |e| <= |a0|+|a1| is
// tiny, so exp() cannot overflow -- identical math to the reference.
// ---------------------------------------------------------------------------
__global__ __launch_bounds__(256) void scatter_kernel(
    const float* __restrict__ rel, const float* __restrict__ attn_e,
    const int* __restrict__ src, const int* __restrict__ dst,
    int* __restrict__ cursor, int2* __restrict__ edata)
{
    int e = blockIdx.x * 256 + threadIdx.x;
    if (e >= N_EDGES) return;
    float a0 = attn_e[0], a1 = attn_e[1];
    float2 r = ((const float2*)rel)[e];
    float sc = r.x * a0 + r.y * a1;
    sc = (sc > 0.f) ? sc : NEG_SLOPE * sc;
    float ev = __expf(sc);
    int d = dst[e];
    int pos = atomicAdd(&cursor[d], 1);        // avg 16 tickets/counter
    edata[pos] = make_int2(src[e], __float_as_int(ev));
}

// ---------------------------------------------------------------------------
// Kernel 4: g = feat @ W_neigh^T ; out = feat @ W_self^T + (b_self+b_neigh)
// Weight columns held in REGISTERS (lane o owns W[o][:], 128 VGPRs), feat
// row values arrive as same-address float4 global loads (HW broadcast).
// Weights transposed through LDS (+1 pad, conflict-free) once per block.
// ---------------------------------------------------------------------------
__global__ __launch_bounds__(256) void gemm_kernel(
    const float* __restrict__ feat, const float* __restrict__ W_self,
    const float* __restrict__ b_self, const float* __restrict__ W_neigh,
    const float* __restrict__ b_neigh, float* __restrict__ g,
    float* __restrict__ out)
{
    __shared__ float Wt[2][D][D + 1];
    int tid = threadIdx.x;
    #pragma unroll
    for (int i = 0; i < 16; ++i) {
        int idx = tid + i * 256;               // coalesced global read
        int o = idx >> 6, k = idx & 63;
        Wt[0][k][o] = W_self[idx];             // transposed store, padded
        Wt[1][k][o] = W_neigh[idx];
    }
    __syncthreads();

    int lane = tid & 63;
    int wave = tid >> 6;
    float ws[D], wn[D];
    #pragma unroll
    for (int k = 0; k < D; ++k) {              // lanes read consecutive o:
        ws[k] = Wt[0][k][lane];                // conflict-free ds_read
        wn[k] = Wt[1][k][lane];
    }
    float bias = b_self[lane] + b_neigh[lane];

    int r0 = blockIdx.x * 64 + wave * 16;      // 16 rows per wave
    #pragma unroll 1
    for (int rr = 0; rr < 16; ++rr) {
        int r = r0 + rr;
        if (r >= N_NODES) return;
        const float4* frow = (const float4*)(feat + (size_t)r * D);
        float accs = 0.f, accn = 0.f;
        #pragma unroll
        for (int k4 = 0; k4 < 16; ++k4) {
            float4 f = frow[k4];               // same addr all lanes: bcast
            accs += f.x * ws[4*k4]   + f.y * ws[4*k4+1]
                  + f.z * ws[4*k4+2] + f.w * ws[4*k4+3];
            accn += f.x * wn[4*k4]   + f.y * wn[4*k4+1]
                  + f.z * wn[4*k4+2] + f.w * wn[4*k4+3];
        }
        out[(size_t)r * D + lane] = accs + bias;
        g[(size_t)r * D + lane] = accn;
    }
}

// ---------------------------------------------------------------------------
// Kernel 5: per-node aggregation, one wave per node, lane = feature.
// out[v] += (sum_e ex_e * g[src_e][lane]) / (sum_e ex_e)
// Denominator computed in-wave -> no denom array, no denom atomics.
// All loads coalesced (g rows) or wave-broadcast (edata). Zero atomics.
// ---------------------------------------------------------------------------
__global__ __launch_bounds__(256) void aggregate_kernel(
    const float* __restrict__ g, const int2* __restrict__ edata,
    const int* __restrict__ offsets, float* __restrict__ out)
{
    int v = blockIdx.x * 4 + (threadIdx.x >> 6);   // 25000*4 == N exactly
    int lane = threadIdx.x & 63;
    int lo = offsets[v], hi = offsets[v + 1];
    float acc = 0.f, sum = 0.f;
    for (int i = lo; i < hi; ++i) {
        int2 ed = edata[i];                        // 8B broadcast load
        float ev = __int_as_float(ed.y);
        acc += ev * g[(size_t)ed.x * D + lane];    // 256B coalesced gather
        sum += ev;
    }
    if (hi > lo) {
        size_t idx = (size_t)v * D + lane;
        out[idx] += acc / sum;
    }
    // zero-degree nodes: reference gives h_neigh = 0 -> out keeps self part
}

// ---------------------------------------------------------------------------
extern "C" void kernel_launch(void* const* d_in, const int* in_sizes, int n_in,
                              void* d_out, int out_size, void* d_ws, size_t ws_size,
                              hipStream_t stream) {
    const float* feat    = (const float*)d_in[0];
    const float* rel     = (const float*)d_in[1];
    const float* W_self  = (const float*)d_in[2];
    const float* b_self  = (const float*)d_in[3];
    const float* W_neigh = (const float*)d_in[4];
    const float* b_neigh = (const float*)d_in[5];
    const float* attn_e  = (const float*)d_in[6];
    const int*   src     = (const int*)d_in[7];
    const int*   dst     = (const int*)d_in[8];
    float* out = (float*)d_out;

    // workspace layout (~39.6 MB)
    float* g       = (float*)d_ws;                       // [N*D]  25.6 MB
    int2*  edata   = (int2*)(g + (size_t)N_NODES * D);   // [E]    12.8 MB
    int*   cnt     = (int*)(edata + N_EDGES);            // [N]
    int*   offsets = cnt + N_NODES;                      // [N+1]
    int*   cursor  = offsets + N_NODES + 1;              // [N]

    hipMemsetAsync(cnt, 0, N_NODES * sizeof(int), stream);

    hist_kernel<<<(N_EDGES + 255) / 256, 256, 0, stream>>>(dst, cnt);
    scan_kernel<<<1, SCAN_T, 0, stream>>>(cnt, offsets, cursor);
    scatter_kernel<<<(N_EDGES + 255) / 256, 256, 0, stream>>>(
        rel, attn_e, src, dst, cursor, edata);
    gemm_kernel<<<(N_NODES + 63) / 64, 256, 0, stream>>>(
        feat, W_self, b_self, W_neigh, b_neigh, g, out);
    aggregate_kernel<<<N_NODES / 4, 256, 0, stream>>>(g, edata, offsets, out);
}

// Round 3
// 529.969 us; speedup vs baseline: 3.0721x; 1.4565x over previous
//
#include <hip/hip_runtime.h>

#define N_NODES 100000
#define N_EDGES 1600000
#define D 64
#define NEG_SLOPE 0.2f
#define NB ((N_NODES + 255) / 256)   // 391 scan blocks

// ---------------------------------------------------------------------------
// Kernel 1: histogram of edges per destination node.
// ---------------------------------------------------------------------------
__global__ __launch_bounds__(256) void hist_kernel(
    const int* __restrict__ dst, int* __restrict__ cnt)
{
    int e = blockIdx.x * 256 + threadIdx.x;
    if (e < N_EDGES) atomicAdd(&cnt[dst[e]], 1);
}

// ---------------------------------------------------------------------------
// Scan phase A: per-block (256-wide) sums of cnt.
// ---------------------------------------------------------------------------
__global__ __launch_bounds__(256) void block_sum_kernel(
    const int* __restrict__ cnt, int* __restrict__ bsum)
{
    int i = blockIdx.x * 256 + threadIdx.x;
    int v = (i < N_NODES) ? cnt[i] : 0;
    #pragma unroll
    for (int o = 32; o > 0; o >>= 1) v += __shfl_down(v, o);
    __shared__ int ws[4];
    if ((threadIdx.x & 63) == 0) ws[threadIdx.x >> 6] = v;
    __syncthreads();
    if (threadIdx.x == 0) bsum[blockIdx.x] = ws[0] + ws[1] + ws[2] + ws[3];
}

// ---------------------------------------------------------------------------
// Scan phase B: exclusive scan of the 391 block sums (single small block).
// ---------------------------------------------------------------------------
__global__ __launch_bounds__(512) void scan_bsum_kernel(
    const int* __restrict__ bsum, int* __restrict__ boff)
{
    __shared__ int sh[512];
    int t = threadIdx.x;
    int v = (t < NB) ? bsum[t] : 0;
    sh[t] = v;
    __syncthreads();
    for (int d = 1; d < 512; d <<= 1) {
        int u = (t >= d) ? sh[t - d] : 0;
        __syncthreads();
        sh[t] += u;
        __syncthreads();
    }
    if (t < NB) boff[t] = sh[t] - v;          // exclusive prefix
}

// ---------------------------------------------------------------------------
// Scan phase C: per-block exclusive scan + block offset -> offsets, cursor.
// ---------------------------------------------------------------------------
__global__ __launch_bounds__(256) void final_scan_kernel(
    const int* __restrict__ cnt, const int* __restrict__ boff,
    int* __restrict__ offsets, int* __restrict__ cursor)
{
    __shared__ int sh[256];
    int t = threadIdx.x;
    int i = blockIdx.x * 256 + t;
    int v = (i < N_NODES) ? cnt[i] : 0;
    sh[t] = v;
    __syncthreads();
    for (int d = 1; d < 256; d <<= 1) {
        int u = (t >= d) ? sh[t - d] : 0;
        __syncthreads();
        sh[t] += u;
        __syncthreads();
    }
    int excl = sh[t] - v + boff[blockIdx.x];
    if (i < N_NODES) { offsets[i] = excl; cursor[i] = excl; }
    if (i == 0) offsets[N_NODES] = N_EDGES;
}

// ---------------------------------------------------------------------------
// Kernel 3: ticket scatter into CSR order. Stores {src, exp(e)} packed as
// int2 so the aggregation loop does ONE 8B broadcast load per edge.
// segment_max skipped: softmax is shift-invariant and |e| <= |a0|+|a1| is
// tiny, so exp() cannot overflow -- identical math to the reference.
// ---------------------------------------------------------------------------
__global__ __launch_bounds__(256) void scatter_kernel(
    const float* __restrict__ rel, const float* __restrict__ attn_e,
    const int* __restrict__ src, const int* __restrict__ dst,
    int* __restrict__ cursor, int2* __restrict__ edata)
{
    int e = blockIdx.x * 256 + threadIdx.x;
    if (e >= N_EDGES) return;
    float a0 = attn_e[0], a1 = attn_e[1];
    float2 r = ((const float2*)rel)[e];
    float sc = r.x * a0 + r.y * a1;
    sc = (sc > 0.f) ? sc : NEG_SLOPE * sc;
    float ev = __expf(sc);
    int d = dst[e];
    int pos = atomicAdd(&cursor[d], 1);        // avg 16 tickets/counter
    edata[pos] = make_int2(src[e], __float_as_int(ev));
}

// ---------------------------------------------------------------------------
// Kernel 4: g = feat @ W_neigh^T ; out = feat @ W_self^T + (b_self+b_neigh)
// Weight columns held in REGISTERS (lane o owns W[o][:], 128 VGPRs), feat
// row values arrive as same-address float4 global loads (HW broadcast).
// Weights transposed through LDS (+1 pad, conflict-free) once per block.
// ---------------------------------------------------------------------------
__global__ __launch_bounds__(256) void gemm_kernel(
    const float* __restrict__ feat, const float* __restrict__ W_self,
    const float* __restrict__ b_self, const float* __restrict__ W_neigh,
    const float* __restrict__ b_neigh, float* __restrict__ g,
    float* __restrict__ out)
{
    __shared__ float Wt[2][D][D + 1];
    int tid = threadIdx.x;
    #pragma unroll
    for (int i = 0; i < 16; ++i) {
        int idx = tid + i * 256;               // coalesced global read
        int o = idx >> 6, k = idx & 63;
        Wt[0][k][o] = W_self[idx];             // transposed store, padded
        Wt[1][k][o] = W_neigh[idx];
    }
    __syncthreads();

    int lane = tid & 63;
    int wave = tid >> 6;
    float ws[D], wn[D];
    #pragma unroll
    for (int k = 0; k < D; ++k) {              // lanes read consecutive o:
        ws[k] = Wt[0][k][lane];                // conflict-free ds_read
        wn[k] = Wt[1][k][lane];
    }
    float bias = b_self[lane] + b_neigh[lane];

    int r0 = blockIdx.x * 64 + wave * 16;      // 16 rows per wave
    #pragma unroll 1
    for (int rr = 0; rr < 16; ++rr) {
        int r = r0 + rr;
        if (r >= N_NODES) return;
        const float4* frow = (const float4*)(feat + (size_t)r * D);
        float accs = 0.f, accn = 0.f;
        #pragma unroll
        for (int k4 = 0; k4 < 16; ++k4) {
            float4 f = frow[k4];               // same addr all lanes: bcast
            accs += f.x * ws[4*k4]   + f.y * ws[4*k4+1]
                  + f.z * ws[4*k4+2] + f.w * ws[4*k4+3];
            accn += f.x * wn[4*k4]   + f.y * wn[4*k4+1]
                  + f.z * wn[4*k4+2] + f.w * wn[4*k4+3];
        }
        out[(size_t)r * D + lane] = accs + bias;
        g[(size_t)r * D + lane] = accn;
    }
}

// ---------------------------------------------------------------------------
// Kernel 5: per-node aggregation, one wave per node, lane = feature.
// out[v] += (sum_e ex_e * g[src_e][lane]) / (sum_e ex_e)
// Denominator computed in-wave -> no denom array, no denom atomics.
// All loads coalesced (g rows) or wave-broadcast (edata). Zero atomics.
// ---------------------------------------------------------------------------
__global__ __launch_bounds__(256) void aggregate_kernel(
    const float* __restrict__ g, const int2* __restrict__ edata,
    const int* __restrict__ offsets, float* __restrict__ out)
{
    int v = blockIdx.x * 4 + (threadIdx.x >> 6);   // 25000*4 == N exactly
    int lane = threadIdx.x & 63;
    int lo = offsets[v], hi = offsets[v + 1];
    float acc = 0.f, sum = 0.f;
    for (int i = lo; i < hi; ++i) {
        int2 ed = edata[i];                        // 8B broadcast load
        float ev = __int_as_float(ed.y);
        acc += ev * g[(size_t)ed.x * D + lane];    // 256B coalesced gather
        sum += ev;
    }
    if (hi > lo) {
        size_t idx = (size_t)v * D + lane;
        out[idx] += acc / sum;
    }
    // zero-degree nodes: reference gives h_neigh = 0 -> out keeps self part
}

// ---------------------------------------------------------------------------
extern "C" void kernel_launch(void* const* d_in, const int* in_sizes, int n_in,
                              void* d_out, int out_size, void* d_ws, size_t ws_size,
                              hipStream_t stream) {
    const float* feat    = (const float*)d_in[0];
    const float* rel     = (const float*)d_in[1];
    const float* W_self  = (const float*)d_in[2];
    const float* b_self  = (const float*)d_in[3];
    const float* W_neigh = (const float*)d_in[4];
    const float* b_neigh = (const float*)d_in[5];
    const float* attn_e  = (const float*)d_in[6];
    const int*   src     = (const int*)d_in[7];
    const int*   dst     = (const int*)d_in[8];
    float* out = (float*)d_out;

    // workspace layout (~40 MB)
    float* g       = (float*)d_ws;                       // [N*D]  25.6 MB
    int2*  edata   = (int2*)(g + (size_t)N_NODES * D);   // [E]    12.8 MB
    int*   cnt     = (int*)(edata + N_EDGES);            // [N]
    int*   offsets = cnt + N_NODES;                      // [N+1]
    int*   cursor  = offsets + N_NODES + 1;              // [N]
    int*   bsum    = cursor + N_NODES;                   // [NB]
    int*   boff    = bsum + NB;                          // [NB]

    hipMemsetAsync(cnt, 0, N_NODES * sizeof(int), stream);

    hist_kernel<<<(N_EDGES + 255) / 256, 256, 0, stream>>>(dst, cnt);
    block_sum_kernel<<<NB, 256, 0, stream>>>(cnt, bsum);
    scan_bsum_kernel<<<1, 512, 0, stream>>>(bsum, boff);
    final_scan_kernel<<<NB, 256, 0, stream>>>(cnt, boff, offsets, cursor);
    scatter_kernel<<<(N_EDGES + 255) / 256, 256, 0, stream>>>(
        rel, attn_e, src, dst, cursor, edata);
    gemm_kernel<<<(N_NODES + 63) / 64, 256, 0, stream>>>(
        feat, W_self, b_self, W_neigh, b_neigh, g, out);
    aggregate_kernel<<<N_NODES / 4, 256, 0, stream>>>(g, edata, offsets, out);
}